// Round 2
// baseline (1764.121 us; speedup 1.0000x reference)
//
#include <hip/hip_runtime.h>
#include <math.h>
#include <stdint.h>

#define NPOS 32768
#define LOG2N 15
#define BATCH 8

__device__ __forceinline__ float fast_tanh(float x) {
    // tanh(x) = 2/(1+exp(-2x)) - 1 ; saturates correctly at +/-inf
    float t = __expf(-2.f * x);
    return fmaf(2.f, __builtin_amdgcn_rcpf(1.f + t), -1.f);
}
__device__ __forceinline__ float fast_sigmoid(float x) {
    return __builtin_amdgcn_rcpf(1.f + __expf(-x));
}

// ---------------- init: h0[b,c,n] = xs[n] + W0[c,0]*xs[n-1] + W0[c,1]*xs[n] + b0[c]
__global__ __launch_bounds__(256) void init_kernel(
    const int* __restrict__ x_int, const float* __restrict__ W0,
    const float* __restrict__ b0, float* __restrict__ h)
{
    int t = blockIdx.x * 256 + threadIdx.x;
    int n = t & (NPOS - 1);
    int b = t >> LOG2N;
    const int* xb = x_int + (size_t)b * NPOS;
    float xs  = (n >= 1) ? (float)xb[n - 1] * (1.f / 32768.f) : 0.f;
    float xsp = (n >= 2) ? (float)xb[n - 2] * (1.f / 32768.f) : 0.f;
    float* hb = h + ((size_t)b * 16) * NPOS + n;
#pragma unroll
    for (int c = 0; c < 16; ++c) {
        hb[(size_t)c * NPOS] = xs + W0[c * 2 + 0] * xsp + W0[c * 2 + 1] * xs + b0[c];
    }
}

// ---------------- one residual layer: f/g dilated conv + skip 1x1 + h update
__global__ __launch_bounds__(256) void layer_kernel(
    const float* __restrict__ hIn, float* __restrict__ hOut,
    float* __restrict__ skip,
    const float* __restrict__ wf, const float* __restrict__ bfv,
    const float* __restrict__ wg, const float* __restrict__ bgv,
    const float* __restrict__ wsk, const float* __restrict__ bskv,
    int d, int firstLayer)
{
    int t = blockIdx.x * 256 + threadIdx.x;
    int n = t & (NPOS - 1);
    int b = t >> LOG2N;
    const float* hb = hIn + ((size_t)b * 16) * NPOS + n;

    float hc[16], hp[16];
#pragma unroll
    for (int ic = 0; ic < 16; ++ic) hc[ic] = hb[(size_t)ic * NPOS];
    if (n >= d) {
#pragma unroll
        for (int ic = 0; ic < 16; ++ic) hp[ic] = hb[(size_t)ic * NPOS - (size_t)d];
    } else {
#pragma unroll
        for (int ic = 0; ic < 16; ++ic) hp[ic] = 0.f;
    }

    float facc[16], gacc[16];
#pragma unroll
    for (int c = 0; c < 16; ++c) { facc[c] = bfv[c]; gacc[c] = bgv[c]; }

#pragma unroll
    for (int c = 0; c < 16; ++c) {
#pragma unroll
        for (int ic = 0; ic < 16; ++ic) {
            facc[c] = fmaf(wf[(c * 16 + ic) * 2 + 0], hp[ic], facc[c]);
            facc[c] = fmaf(wf[(c * 16 + ic) * 2 + 1], hc[ic], facc[c]);
            gacc[c] = fmaf(wg[(c * 16 + ic) * 2 + 0], hp[ic], gacc[c]);
            gacc[c] = fmaf(wg[(c * 16 + ic) * 2 + 1], hc[ic], gacc[c]);
        }
    }

    // skip accumulation (uses pre-update h, as in reference)
    float* skb = skip + ((size_t)b * 32) * NPOS + n;
#pragma unroll
    for (int sc = 0; sc < 32; ++sc) {
        float acc = bskv[sc];
#pragma unroll
        for (int ic = 0; ic < 16; ++ic) acc = fmaf(wsk[sc * 16 + ic], hc[ic], acc);
        if (firstLayer) skb[(size_t)sc * NPOS] = acc;
        else            skb[(size_t)sc * NPOS] += acc;
    }

    float* ho = hOut + ((size_t)b * 16) * NPOS + n;
#pragma unroll
    for (int c = 0; c < 16; ++c) {
        float fv = fast_tanh(facc[c]);
        float gv = fast_sigmoid(gacc[c]);
        ho[(size_t)c * NPOS] = hc[c] + fv * gv;
    }
}

// ---------------- final: relu(skip) -> agg(64) -> relu -> logits(256) -> log_softmax
// block = 256 threads = 4 waves, covers 64 consecutive positions (lane = position).
// Stage 1: wave w computes agg channels [16w,16w+16) -> LDS.
// Stage 2: wave w computes classes [64w,64w+64), online max/sum (no lg[] array!),
//          raw logits streamed to d_out, then re-read (L2-hot) and shifted by logZ.
__global__ __launch_bounds__(256) void final_kernel(
    const float* __restrict__ skip,
    const float* __restrict__ Wagg, const float* __restrict__ bagg,
    const float* __restrict__ Wout, const float* __restrict__ bout,
    float* out)
{
    __shared__ float agg_lds[64][64];   // [agg_ch][pos] : fixed-row access -> conflict-free
    __shared__ float red_m[64][4];
    __shared__ float red_s[64][4];

    int lane = threadIdx.x & 63;
    int cg = (int)(threadIdx.x >> 6);   // wave index (uniform)
    size_t pos = (size_t)blockIdx.x * 64 + (size_t)lane;
    int n = (int)(pos & (NPOS - 1));
    int b = (int)(pos >> LOG2N);

    // ---- stage 1: cooperative agg
    const float* skb = skip + ((size_t)b * 32) * NPOS + n;
    float sv[32];
#pragma unroll
    for (int sc = 0; sc < 32; ++sc) sv[sc] = fmaxf(skb[(size_t)sc * NPOS], 0.f);

#pragma unroll
    for (int a = 0; a < 16; ++a) {
        int ac = cg * 16 + a;
        float acc = bagg[ac];
#pragma unroll
        for (int sc = 0; sc < 32; ++sc) acc = fmaf(Wagg[ac * 32 + sc], sv[sc], acc);
        agg_lds[ac][lane] = fmaxf(acc, 0.f);
    }
    __syncthreads();

    float agg[64];
#pragma unroll
    for (int ic = 0; ic < 64; ++ic) agg[ic] = agg_lds[ic][lane];

    float* ob = out + ((size_t)b * 256 + (size_t)cg * 64) * NPOS + n;

    // ---- stage 2: classes with online softmax stats, raw logits -> global
    float m = -1e30f, s = 0.f;
    for (int j = 0; j < 64; ++j) {
        const float* wrow = Wout + ((size_t)(cg * 64 + j)) * 64;
        float acc = bout[cg * 64 + j];
#pragma unroll
        for (int ic = 0; ic < 64; ++ic) acc = fmaf(wrow[ic], agg[ic], acc);
        ob[(size_t)j * NPOS] = acc;
        float m2 = fmaxf(m, acc);
        s = s * __expf(m - m2) + __expf(acc - m2);
        m = m2;
    }

    red_m[lane][cg] = m;
    red_s[lane][cg] = s;
    __syncthreads();

    float M = fmaxf(fmaxf(red_m[lane][0], red_m[lane][1]),
                    fmaxf(red_m[lane][2], red_m[lane][3]));
    float S = 0.f;
#pragma unroll
    for (int k = 0; k < 4; ++k) S += red_s[lane][k] * __expf(red_m[lane][k] - M);
    float logZ = M + __logf(S);

    // ---- pass 2b: shift own logits (same-thread RAW through L1/L2, coalesced)
    for (int j = 0; j < 64; ++j) {
        float v = ob[(size_t)j * NPOS];
        ob[(size_t)j * NPOS] = v - logZ;
    }
}

extern "C" void kernel_launch(void* const* d_in, const int* in_sizes, int n_in,
                              void* d_out, int out_size, void* d_ws, size_t ws_size,
                              hipStream_t stream)
{
    const int*   x_int = (const int*)  d_in[0];
    const float* W0    = (const float*)d_in[1];
    const float* b0    = (const float*)d_in[2];
    const float* Wf    = (const float*)d_in[3];
    const float* bf    = (const float*)d_in[4];
    const float* Wg    = (const float*)d_in[5];
    const float* bg    = (const float*)d_in[6];
    const float* Wsk   = (const float*)d_in[7];
    const float* bsk   = (const float*)d_in[8];
    const float* Wagg  = (const float*)d_in[9];
    const float* bagg  = (const float*)d_in[10];
    const float* Wout  = (const float*)d_in[11];
    const float* bout  = (const float*)d_in[12];
    float* out = (float*)d_out;

    const size_t hElems  = (size_t)BATCH * 16 * NPOS; // 4M floats = 16 MiB
    const size_t skElems = (size_t)BATCH * 32 * NPOS; // 8M floats = 32 MiB

    float *skip, *hA, *hB;
    char* ws = (char*)d_ws;
    if (ws_size >= (hElems * 2 + skElems) * sizeof(float)) {
        skip = (float*)ws;
        hA   = (float*)(ws + skElems * sizeof(float));
        hB   = hA + hElems;
    } else if (ws_size >= skElems * sizeof(float)) {
        skip = (float*)ws;
        hA   = out + ((size_t)out_size - 2 * hElems);
        hB   = hA + hElems;
    } else {
        skip = out + ((size_t)out_size - skElems - 2 * hElems);
        hA   = skip + skElems;
        hB   = hA + hElems;
    }

    const int totalPos = BATCH * NPOS; // 262144

    init_kernel<<<totalPos / 256, 256, 0, stream>>>(x_int, W0, b0, hA);

    float* hin = hA;
    float* hout = hB;
    for (int i = 0; i < 19; ++i) {
        int d = 1 << ((i + 1) % 10);
        layer_kernel<<<totalPos / 256, 256, 0, stream>>>(
            hin, hout, skip,
            Wf + (size_t)i * 16 * 16 * 2, bf + (size_t)i * 16,
            Wg + (size_t)i * 16 * 16 * 2, bg + (size_t)i * 16,
            Wsk + (size_t)i * 32 * 16,    bsk + (size_t)i * 32,
            d, (i == 0) ? 1 : 0);
        float* tmp = hin; hin = hout; hout = tmp;
    }

    final_kernel<<<totalPos / 64, 256, 0, stream>>>(skip, Wagg, bagg, Wout, bout, out);
}

// Round 5
// 1592.481 us; speedup vs baseline: 1.1078x; 1.1078x over previous
//
#include <hip/hip_runtime.h>
#include <hip/hip_cooperative_groups.h>
#include <math.h>
#include <stdint.h>

namespace cg = cooperative_groups;

#define NPOS  32768
#define LOG2N 15
#define BATCH 8
#define TOTAL (BATCH * NPOS)   // 262144 positions
#define CBLK  512              // cooperative grid blocks
#define PPT   2                // positions per thread (coop path)

// Layouts (BOTH paths): h buffers = [16][TOTAL], skip = [32][TOTAL], t = b*NPOS+n.

__device__ __forceinline__ float fast_tanh(float x) {
    float t = __expf(-2.f * x);
    return fmaf(2.f, __builtin_amdgcn_rcpf(1.f + t), -1.f);
}
__device__ __forceinline__ float fast_sigmoid(float x) {
    return __builtin_amdgcn_rcpf(1.f + __expf(-x));
}

// ================= cooperative layers kernel =================
__global__ __launch_bounds__(256, 3) void wavenet_layers(
    const int* __restrict__ x_int,
    const float* __restrict__ W0,  const float* __restrict__ b0,
    const float* __restrict__ Wf,  const float* __restrict__ bfv,
    const float* __restrict__ Wg,  const float* __restrict__ bgv,
    const float* __restrict__ Wsk, const float* __restrict__ bskv,
    float* __restrict__ hbufA, float* __restrict__ hbufB,
    float* __restrict__ skipbuf)
{
    cg::grid_group grid = cg::this_grid();
    int t0 = blockIdx.x * (256 * PPT) + threadIdx.x;

    float h[PPT][16], skip[PPT][32];

#pragma unroll
    for (int p = 0; p < PPT; ++p) {
        int t = t0 + p * 256;
        int n = t & (NPOS - 1);
        float xs  = (n >= 1) ? (float)x_int[t - 1] * (1.f / 32768.f) : 0.f;
        float xsp = (n >= 2) ? (float)x_int[t - 2] * (1.f / 32768.f) : 0.f;
#pragma unroll
        for (int c = 0; c < 16; ++c)
            h[p][c] = xs + W0[c * 2 + 0] * xsp + W0[c * 2 + 1] * xs + b0[c];
#pragma unroll
        for (int sc = 0; sc < 32; ++sc) skip[p][sc] = 0.f;
    }

    for (int i = 0; i < 19; ++i) {
        int d = 1 << ((i + 1) % 10);
        float* wb = (i & 1) ? hbufB : hbufA;

        // 1) publish h_i
#pragma unroll
        for (int p = 0; p < PPT; ++p) {
            int t = t0 + p * 256;
#pragma unroll
            for (int c = 0; c < 16; ++c) wb[(size_t)c * TOTAL + t] = h[p][c];
        }

        // 2) skip += Wsk_i * h_i + bsk_i (pre-update h)
        const float* wskL = Wsk + (size_t)i * 512;
        const float* bskL = bskv + i * 32;
#pragma unroll
        for (int p = 0; p < PPT; ++p) {
#pragma unroll
            for (int sc = 0; sc < 32; ++sc) {
                float acc = bskL[sc];
#pragma unroll
                for (int ic = 0; ic < 16; ++ic)
                    acc = fmaf(wskL[sc * 16 + ic], h[p][ic], acc);
                skip[p][sc] += acc;
            }
        }

        // 3) grid-wide barrier
        grid.sync();

        // 4+5) dilated read + gated conv + residual
        const float* wfL = Wf + (size_t)i * 512;
        const float* wgL = Wg + (size_t)i * 512;
        const float* bfL = bfv + i * 16;
        const float* bgL = bgv + i * 16;
#pragma unroll
        for (int p = 0; p < PPT; ++p) {
            int t = t0 + p * 256;
            int n = t & (NPOS - 1);
            int tm = (n >= d) ? (t - d) : t;
            float hp[16];
#pragma unroll
            for (int c = 0; c < 16; ++c) {
                float v = wb[(size_t)c * TOTAL + tm];
                hp[c] = (n >= d) ? v : 0.f;
            }
            float nh[16];
#pragma unroll
            for (int c = 0; c < 16; ++c) {
                float fa = bfL[c], ga = bgL[c];
#pragma unroll
                for (int ic = 0; ic < 16; ++ic) {
                    fa = fmaf(wfL[(c * 16 + ic) * 2 + 0], hp[ic], fa);
                    fa = fmaf(wfL[(c * 16 + ic) * 2 + 1], h[p][ic], fa);
                    ga = fmaf(wgL[(c * 16 + ic) * 2 + 0], hp[ic], ga);
                    ga = fmaf(wgL[(c * 16 + ic) * 2 + 1], h[p][ic], ga);
                }
                nh[c] = fmaf(fast_tanh(fa), fast_sigmoid(ga), h[p][c]);
            }
#pragma unroll
            for (int c = 0; c < 16; ++c) h[p][c] = nh[c];
        }
    }

#pragma unroll
    for (int p = 0; p < PPT; ++p) {
        int t = t0 + p * 256;
#pragma unroll
        for (int sc = 0; sc < 32; ++sc)
            skipbuf[(size_t)sc * TOTAL + t] = skip[p][sc];
    }
}

// ================= fallback path (R2 structure, unified layouts) =============
__global__ __launch_bounds__(256) void init_kernel(
    const int* __restrict__ x_int, const float* __restrict__ W0,
    const float* __restrict__ b0, float* __restrict__ h)
{
    int t = blockIdx.x * 256 + threadIdx.x;
    int n = t & (NPOS - 1);
    float xs  = (n >= 1) ? (float)x_int[t - 1] * (1.f / 32768.f) : 0.f;
    float xsp = (n >= 2) ? (float)x_int[t - 2] * (1.f / 32768.f) : 0.f;
#pragma unroll
    for (int c = 0; c < 16; ++c)
        h[(size_t)c * TOTAL + t] = xs + W0[c * 2 + 0] * xsp + W0[c * 2 + 1] * xs + b0[c];
}

__global__ __launch_bounds__(256) void layer_kernel(
    const float* __restrict__ hIn, float* __restrict__ hOut,
    float* __restrict__ skip,
    const float* __restrict__ wf, const float* __restrict__ bfv,
    const float* __restrict__ wg, const float* __restrict__ bgv,
    const float* __restrict__ wsk, const float* __restrict__ bskv,
    int d, int firstLayer)
{
    int t = blockIdx.x * 256 + threadIdx.x;
    int n = t & (NPOS - 1);

    float hc[16], hp[16];
#pragma unroll
    for (int ic = 0; ic < 16; ++ic) hc[ic] = hIn[(size_t)ic * TOTAL + t];
    int tm = (n >= d) ? (t - d) : t;
#pragma unroll
    for (int ic = 0; ic < 16; ++ic) {
        float v = hIn[(size_t)ic * TOTAL + tm];
        hp[ic] = (n >= d) ? v : 0.f;
    }

    float facc[16], gacc[16];
#pragma unroll
    for (int c = 0; c < 16; ++c) { facc[c] = bfv[c]; gacc[c] = bgv[c]; }
#pragma unroll
    for (int c = 0; c < 16; ++c) {
#pragma unroll
        for (int ic = 0; ic < 16; ++ic) {
            facc[c] = fmaf(wf[(c * 16 + ic) * 2 + 0], hp[ic], facc[c]);
            facc[c] = fmaf(wf[(c * 16 + ic) * 2 + 1], hc[ic], facc[c]);
            gacc[c] = fmaf(wg[(c * 16 + ic) * 2 + 0], hp[ic], gacc[c]);
            gacc[c] = fmaf(wg[(c * 16 + ic) * 2 + 1], hc[ic], gacc[c]);
        }
    }

#pragma unroll
    for (int sc = 0; sc < 32; ++sc) {
        float acc = bskv[sc];
#pragma unroll
        for (int ic = 0; ic < 16; ++ic) acc = fmaf(wsk[sc * 16 + ic], hc[ic], acc);
        size_t idx = (size_t)sc * TOTAL + t;
        if (firstLayer) skip[idx] = acc;
        else            skip[idx] += acc;
    }

#pragma unroll
    for (int c = 0; c < 16; ++c)
        hOut[(size_t)c * TOTAL + t] = fmaf(fast_tanh(facc[c]), fast_sigmoid(gacc[c]), hc[c]);
}

// ================= final: relu(skip)->agg64->relu->logits256->log_softmax ====
__global__ __launch_bounds__(256, 2) void final_kernel(
    const float* __restrict__ skip,
    const float* __restrict__ Wagg, const float* __restrict__ bagg,
    const float* __restrict__ Wout, const float* __restrict__ bout,
    float* __restrict__ out)
{
    __shared__ float agg_lds[64][64];
    __shared__ float red_m[64][4];
    __shared__ float red_s[64][4];

    int lane = threadIdx.x & 63;
    int cgw  = threadIdx.x >> 6;
    int pos  = blockIdx.x * 64 + lane;
    int n = pos & (NPOS - 1);
    int b = pos >> LOG2N;

    float sv[32];
#pragma unroll
    for (int sc = 0; sc < 32; ++sc)
        sv[sc] = fmaxf(skip[(size_t)sc * TOTAL + pos], 0.f);

#pragma unroll
    for (int a = 0; a < 16; ++a) {
        int ac = cgw * 16 + a;
        float acc = bagg[ac];
#pragma unroll
        for (int sc = 0; sc < 32; ++sc)
            acc = fmaf(Wagg[ac * 32 + sc], sv[sc], acc);
        agg_lds[ac][lane] = fmaxf(acc, 0.f);
    }
    __syncthreads();

    unsigned stash[32];
    float m = -1e30f, s = 0.f;
    int c0 = cgw * 64;
#pragma unroll
    for (int jt = 0; jt < 8; ++jt) {
        float acc[8];
#pragma unroll
        for (int k = 0; k < 8; ++k) acc[k] = bout[c0 + jt * 8 + k];
#pragma unroll
        for (int ic = 0; ic < 64; ++ic) {
            float a = agg_lds[ic][lane];
#pragma unroll
            for (int k = 0; k < 8; ++k)
                acc[k] = fmaf(Wout[(size_t)(c0 + jt * 8 + k) * 64 + ic], a, acc[k]);
        }
        float mx = acc[0];
#pragma unroll
        for (int k = 1; k < 8; ++k) mx = fmaxf(mx, acc[k]);
        float m2 = fmaxf(m, mx);
        float ssum = 0.f;
#pragma unroll
        for (int k = 0; k < 8; ++k) ssum += __expf(acc[k] - m2);
        s = s * __expf(m - m2) + ssum;
        m = m2;
#pragma unroll
        for (int k = 0; k < 4; ++k) {
            unsigned lo = __float_as_uint(acc[2 * k]);
            unsigned hi = __float_as_uint(acc[2 * k + 1]);
            lo = (lo + 0x7fffu + ((lo >> 16) & 1u)) >> 16;
            hi = (hi + 0x7fffu + ((hi >> 16) & 1u)) & 0xffff0000u;
            stash[jt * 4 + k] = lo | hi;
        }
    }

    red_m[lane][cgw] = m;
    red_s[lane][cgw] = s;
    __syncthreads();
    float M = fmaxf(fmaxf(red_m[lane][0], red_m[lane][1]),
                    fmaxf(red_m[lane][2], red_m[lane][3]));
    float S = 0.f;
#pragma unroll
    for (int k = 0; k < 4; ++k) S += red_s[lane][k] * __expf(red_m[lane][k] - M);
    float logZ = M + __logf(S);

    float* ob = out + ((size_t)(b * 256 + c0)) * NPOS + n;
#pragma unroll
    for (int q = 0; q < 32; ++q) {
        unsigned pk = stash[q];
        float v0 = __uint_as_float(pk << 16);
        float v1 = __uint_as_float(pk & 0xffff0000u);
        ob[(size_t)(2 * q)     * NPOS] = v0 - logZ;
        ob[(size_t)(2 * q + 1) * NPOS] = v1 - logZ;
    }
}

extern "C" void kernel_launch(void* const* d_in, const int* in_sizes, int n_in,
                              void* d_out, int out_size, void* d_ws, size_t ws_size,
                              hipStream_t stream)
{
    const int*   x_int = (const int*)  d_in[0];
    const float* W0    = (const float*)d_in[1];
    const float* b0    = (const float*)d_in[2];
    const float* Wf    = (const float*)d_in[3];
    const float* bfv   = (const float*)d_in[4];
    const float* Wg    = (const float*)d_in[5];
    const float* bgv   = (const float*)d_in[6];
    const float* Wsk   = (const float*)d_in[7];
    const float* bskv  = (const float*)d_in[8];
    const float* Wagg  = (const float*)d_in[9];
    const float* bagg  = (const float*)d_in[10];
    const float* Wout  = (const float*)d_in[11];
    const float* bout  = (const float*)d_in[12];
    float* out = (float*)d_out;

    const size_t hE  = (size_t)16 * TOTAL;  // 16 MiB
    const size_t skE = (size_t)32 * TOTAL;  // 32 MiB

    // skip must NOT live in d_out (final_kernel writes all of out while other
    // blocks still read skip). h ping-pong MAY live in the out tail (dead by
    // the time final_kernel runs).
    float* skipb;
    float *hA, *hB;
    if (ws_size >= (skE + 2 * hE) * sizeof(float)) {
        skipb = (float*)d_ws;
        hA = skipb + skE;
        hB = hA + hE;
    } else if (ws_size >= skE * sizeof(float)) {
        skipb = (float*)d_ws;
        hA = out + ((size_t)out_size - 2 * hE);
        hB = hA + hE;
    } else {
        // untested-size fallback: put skip at ws start anyway (best effort)
        skipb = (float*)d_ws;
        hA = out + ((size_t)out_size - 2 * hE);
        hB = hA + hE;
    }

    // ---- decide whether the cooperative launch can work
    int dev = 0;
    (void)hipGetDevice(&dev);
    int coopAttr = 0, numCU = 0;
    (void)hipDeviceGetAttribute(&coopAttr, hipDeviceAttributeCooperativeLaunch, dev);
    (void)hipDeviceGetAttribute(&numCU, hipDeviceAttributeMultiprocessorCount, dev);
    int blocksPerCU = 0;
    (void)hipOccupancyMaxActiveBlocksPerMultiprocessor(
        &blocksPerCU, (const void*)wavenet_layers, 256, 0);

    bool coopDone = false;
    if (coopAttr && numCU > 0 && blocksPerCU > 0 &&
        (long)blocksPerCU * numCU >= CBLK) {
        void* args[] = {
            (void*)&x_int, (void*)&W0, (void*)&b0,
            (void*)&Wf, (void*)&bfv, (void*)&Wg, (void*)&bgv,
            (void*)&Wsk, (void*)&bskv,
            (void*)&hA, (void*)&hB, (void*)&skipb
        };
        hipError_t cerr = hipLaunchCooperativeKernel(
            (const void*)wavenet_layers, dim3(CBLK), dim3(256), args, 0, stream);
        coopDone = (cerr == hipSuccess);
    }

    if (!coopDone) {
        init_kernel<<<TOTAL / 256, 256, 0, stream>>>(x_int, W0, b0, hA);
        float* hin = hA;
        float* hout = hB;
        for (int i = 0; i < 19; ++i) {
            int d = 1 << ((i + 1) % 10);
            layer_kernel<<<TOTAL / 256, 256, 0, stream>>>(
                hin, hout, skipb,
                Wf + (size_t)i * 512, bfv + (size_t)i * 16,
                Wg + (size_t)i * 512, bgv + (size_t)i * 16,
                Wsk + (size_t)i * 512, bskv + (size_t)i * 32,
                d, (i == 0) ? 1 : 0);
            float* tmp = hin; hin = hout; hout = tmp;
        }
    }

    final_kernel<<<TOTAL / 64, 256, 0, stream>>>(skipb, Wagg, bagg, Wout, bout, out);
}

// Round 6
// 1294.665 us; speedup vs baseline: 1.3626x; 1.2300x over previous
//
#include <hip/hip_runtime.h>
#include <math.h>
#include <stdint.h>

#define NPOS  32768
#define LOG2N 15
#define BATCH 8
#define TOTAL (BATCH * NPOS)   // 262144 positions

// Layouts: h buffers = [16][TOTAL], skip = [32][TOTAL], t = b*NPOS+n.
// All kernels process 2 consecutive positions per thread (float2, t0 even).

__device__ __forceinline__ float fast_tanh(float x) {
    float t = __expf(-2.f * x);
    return fmaf(2.f, __builtin_amdgcn_rcpf(1.f + t), -1.f);
}
__device__ __forceinline__ float fast_sigmoid(float x) {
    return __builtin_amdgcn_rcpf(1.f + __expf(-x));
}

// ================= init =================
__global__ __launch_bounds__(256) void init_kernel2(
    const int* __restrict__ x_int, const float* __restrict__ W0,
    const float* __restrict__ b0, float* __restrict__ h)
{
    int t0 = (blockIdx.x * 256 + threadIdx.x) * 2;
    int n0 = t0 & (NPOS - 1);
    const float sc = 1.f / 32768.f;
    // shifted signal: xs(n) = x[n-1] (n>=1), xsp(n) = x[n-2] (n>=2)
    float xs0  = (n0 >= 1) ? (float)x_int[t0 - 1] * sc : 0.f;
    float xs1  = (float)x_int[t0] * sc;                       // n0+1 >= 1 always
    float xsp0 = (n0 >= 2) ? (float)x_int[t0 - 2] * sc : 0.f;
    float xsp1 = xs0;                                          // same gate (n0 even)
#pragma unroll
    for (int c = 0; c < 16; ++c) {
        float2 o;
        o.x = xs0 + W0[c * 2 + 0] * xsp0 + W0[c * 2 + 1] * xs0 + b0[c];
        o.y = xs1 + W0[c * 2 + 0] * xsp1 + W0[c * 2 + 1] * xs1 + b0[c];
        *(float2*)(h + (size_t)c * TOTAL + t0) = o;
    }
}

// ================= one residual layer (float2 vectorized) =================
__global__ __launch_bounds__(256, 2) void layer_kernel2(
    const float* __restrict__ hIn, float* __restrict__ hOut,
    float* __restrict__ skip,
    const float* __restrict__ wf, const float* __restrict__ bfv,
    const float* __restrict__ wg, const float* __restrict__ bgv,
    const float* __restrict__ wsk, const float* __restrict__ bskv,
    int d, int firstLayer)
{
    int t0 = (blockIdx.x * 256 + threadIdx.x) * 2;
    int n0 = t0 & (NPOS - 1);

    float2 hc[16], hp[16];
#pragma unroll
    for (int ic = 0; ic < 16; ++ic)
        hc[ic] = *(const float2*)(hIn + (size_t)ic * TOTAL + t0);

    if (d == 1) {
        // lane0 needs h[t0-1] (valid iff n0>=1); lane1 needs h[t0] = hc.x
        bool v = (n0 >= 1);
        int tm = v ? (t0 - 1) : t0;
#pragma unroll
        for (int ic = 0; ic < 16; ++ic) {
            float x = hIn[(size_t)ic * TOTAL + tm];
            hp[ic].x = v ? x : 0.f;
            hp[ic].y = hc[ic].x;
        }
    } else {
        // d even, n0 even -> both lanes share the validity predicate (n0>=d)
        bool v = (n0 >= d);
        int tm = v ? (t0 - d) : t0;
#pragma unroll
        for (int ic = 0; ic < 16; ++ic) {
            float2 x = *(const float2*)(hIn + (size_t)ic * TOTAL + tm);
            hp[ic].x = v ? x.x : 0.f;
            hp[ic].y = v ? x.y : 0.f;
        }
    }

    float2 fa[16], ga[16];
#pragma unroll
    for (int c = 0; c < 16; ++c) {
        fa[c].x = fa[c].y = bfv[c];
        ga[c].x = ga[c].y = bgv[c];
    }
#pragma unroll
    for (int c = 0; c < 16; ++c) {
#pragma unroll
        for (int ic = 0; ic < 16; ++ic) {
            float wf0 = wf[(c * 16 + ic) * 2 + 0];
            float wf1 = wf[(c * 16 + ic) * 2 + 1];
            float wg0 = wg[(c * 16 + ic) * 2 + 0];
            float wg1 = wg[(c * 16 + ic) * 2 + 1];
            fa[c].x = fmaf(wf0, hp[ic].x, fa[c].x);
            fa[c].x = fmaf(wf1, hc[ic].x, fa[c].x);
            fa[c].y = fmaf(wf0, hp[ic].y, fa[c].y);
            fa[c].y = fmaf(wf1, hc[ic].y, fa[c].y);
            ga[c].x = fmaf(wg0, hp[ic].x, ga[c].x);
            ga[c].x = fmaf(wg1, hc[ic].x, ga[c].x);
            ga[c].y = fmaf(wg0, hp[ic].y, ga[c].y);
            ga[c].y = fmaf(wg1, hc[ic].y, ga[c].y);
        }
    }

    // h update first (frees hp/fa/ga before the skip phase)
#pragma unroll
    for (int c = 0; c < 16; ++c) {
        float2 o;
        o.x = fmaf(fast_tanh(fa[c].x), fast_sigmoid(ga[c].x), hc[c].x);
        o.y = fmaf(fast_tanh(fa[c].y), fast_sigmoid(ga[c].y), hc[c].y);
        *(float2*)(hOut + (size_t)c * TOTAL + t0) = o;
    }

    // skip accumulation from PRE-update h (hc)
#pragma unroll
    for (int sch = 0; sch < 32; ++sch) {
        float2 acc;
        acc.x = acc.y = bskv[sch];
#pragma unroll
        for (int ic = 0; ic < 16; ++ic) {
            float w = wsk[sch * 16 + ic];
            acc.x = fmaf(w, hc[ic].x, acc.x);
            acc.y = fmaf(w, hc[ic].y, acc.y);
        }
        float* sp = skip + (size_t)sch * TOTAL + t0;
        if (firstLayer) {
            *(float2*)sp = acc;
        } else {
            float2 old = *(const float2*)sp;
            acc.x += old.x; acc.y += old.y;
            *(float2*)sp = acc;
        }
    }
}

// ================= final: relu(skip)->agg64->relu->logits256->log_softmax ====
__global__ __launch_bounds__(256, 2) void final_kernel(
    const float* __restrict__ skip,
    const float* __restrict__ Wagg, const float* __restrict__ bagg,
    const float* __restrict__ Wout, const float* __restrict__ bout,
    float* __restrict__ out)
{
    __shared__ float agg_lds[64][64];
    __shared__ float red_m[64][4];
    __shared__ float red_s[64][4];

    int lane = threadIdx.x & 63;
    int cgw  = threadIdx.x >> 6;
    int pos  = blockIdx.x * 64 + lane;
    int n = pos & (NPOS - 1);
    int b = pos >> LOG2N;

    float sv[32];
#pragma unroll
    for (int sch = 0; sch < 32; ++sch)
        sv[sch] = fmaxf(skip[(size_t)sch * TOTAL + pos], 0.f);

#pragma unroll
    for (int a = 0; a < 16; ++a) {
        int ac = cgw * 16 + a;
        float acc = bagg[ac];
#pragma unroll
        for (int sch = 0; sch < 32; ++sch)
            acc = fmaf(Wagg[ac * 32 + sch], sv[sch], acc);
        agg_lds[ac][lane] = fmaxf(acc, 0.f);
    }
    __syncthreads();

    unsigned stash[32];
    float m = -1e30f, s = 0.f;
    int c0 = cgw * 64;
#pragma unroll
    for (int jt = 0; jt < 8; ++jt) {
        float acc[8];
#pragma unroll
        for (int k = 0; k < 8; ++k) acc[k] = bout[c0 + jt * 8 + k];
#pragma unroll
        for (int ic = 0; ic < 64; ++ic) {
            float a = agg_lds[ic][lane];
#pragma unroll
            for (int k = 0; k < 8; ++k)
                acc[k] = fmaf(Wout[(size_t)(c0 + jt * 8 + k) * 64 + ic], a, acc[k]);
        }
        float mx = acc[0];
#pragma unroll
        for (int k = 1; k < 8; ++k) mx = fmaxf(mx, acc[k]);
        float m2 = fmaxf(m, mx);
        float ssum = 0.f;
#pragma unroll
        for (int k = 0; k < 8; ++k) ssum += __expf(acc[k] - m2);
        s = s * __expf(m - m2) + ssum;
        m = m2;
#pragma unroll
        for (int k = 0; k < 4; ++k) {
            unsigned lo = __float_as_uint(acc[2 * k]);
            unsigned hi = __float_as_uint(acc[2 * k + 1]);
            lo = (lo + 0x7fffu + ((lo >> 16) & 1u)) >> 16;
            hi = (hi + 0x7fffu + ((hi >> 16) & 1u)) & 0xffff0000u;
            stash[jt * 4 + k] = lo | hi;
        }
    }

    red_m[lane][cgw] = m;
    red_s[lane][cgw] = s;
    __syncthreads();
    float M = fmaxf(fmaxf(red_m[lane][0], red_m[lane][1]),
                    fmaxf(red_m[lane][2], red_m[lane][3]));
    float S = 0.f;
#pragma unroll
    for (int k = 0; k < 4; ++k) S += red_s[lane][k] * __expf(red_m[lane][k] - M);
    float logZ = M + __logf(S);

    float* ob = out + ((size_t)(b * 256 + c0)) * NPOS + n;
#pragma unroll
    for (int q = 0; q < 32; ++q) {
        unsigned pk = stash[q];
        float v0 = __uint_as_float(pk << 16);
        float v1 = __uint_as_float(pk & 0xffff0000u);
        ob[(size_t)(2 * q)     * NPOS] = v0 - logZ;
        ob[(size_t)(2 * q + 1) * NPOS] = v1 - logZ;
    }
}

extern "C" void kernel_launch(void* const* d_in, const int* in_sizes, int n_in,
                              void* d_out, int out_size, void* d_ws, size_t ws_size,
                              hipStream_t stream)
{
    const int*   x_int = (const int*)  d_in[0];
    const float* W0    = (const float*)d_in[1];
    const float* b0    = (const float*)d_in[2];
    const float* Wf    = (const float*)d_in[3];
    const float* bfv   = (const float*)d_in[4];
    const float* Wg    = (const float*)d_in[5];
    const float* bgv   = (const float*)d_in[6];
    const float* Wsk   = (const float*)d_in[7];
    const float* bskv  = (const float*)d_in[8];
    const float* Wagg  = (const float*)d_in[9];
    const float* bagg  = (const float*)d_in[10];
    const float* Wout  = (const float*)d_in[11];
    const float* bout  = (const float*)d_in[12];
    float* out = (float*)d_out;

    const size_t hE  = (size_t)16 * TOTAL;  // 16 MiB
    const size_t skE = (size_t)32 * TOTAL;  // 32 MiB

    // skip must NOT live in d_out (final_kernel reads skip while writing out).
    // h ping-pong MAY live in the out tail (dead before final_kernel runs).
    float* skipb = (float*)d_ws;
    float *hA, *hB;
    if (ws_size >= (skE + 2 * hE) * sizeof(float)) {
        hA = skipb + skE;
        hB = hA + hE;
    } else {
        hA = out + ((size_t)out_size - 2 * hE);
        hB = hA + hE;
    }

    const int grid2 = TOTAL / (256 * 2);   // 512 blocks, 2 positions/thread

    init_kernel2<<<grid2, 256, 0, stream>>>(x_int, W0, b0, hA);

    float* hin = hA;
    float* hout = hB;
    for (int i = 0; i < 19; ++i) {
        int d = 1 << ((i + 1) % 10);
        layer_kernel2<<<grid2, 256, 0, stream>>>(
            hin, hout, skipb,
            Wf + (size_t)i * 512, bfv + (size_t)i * 16,
            Wg + (size_t)i * 512, bgv + (size_t)i * 16,
            Wsk + (size_t)i * 512, bskv + (size_t)i * 32,
            d, (i == 0) ? 1 : 0);
        float* tmp = hin; hin = hout; hout = tmp;
    }

    final_kernel<<<TOTAL / 64, 256, 0, stream>>>(skipb, Wagg, bagg, Wout, bout, out);
}

// Round 7
// 1241.814 us; speedup vs baseline: 1.4206x; 1.0426x over previous
//
#include <hip/hip_runtime.h>
#include <math.h>
#include <stdint.h>

#define NPOS  32768
#define LOG2N 15
#define BATCH 8
#define TOTAL (BATCH * NPOS)   // 262144 positions

// Layouts: h buffers = [16][TOTAL], skip = [32][TOTAL], t = b*NPOS+n.
// Layer kernels process 2 consecutive positions per thread (float2, t0 even).

__device__ __forceinline__ float fast_tanh(float x) {
    float t = __expf(-2.f * x);
    return fmaf(2.f, __builtin_amdgcn_rcpf(1.f + t), -1.f);
}
__device__ __forceinline__ float fast_sigmoid(float x) {
    return __builtin_amdgcn_rcpf(1.f + __expf(-x));
}

// ================= init =================
__global__ __launch_bounds__(256) void init_kernel2(
    const int* __restrict__ x_int, const float* __restrict__ W0,
    const float* __restrict__ b0, float* __restrict__ h)
{
    int t0 = (blockIdx.x * 256 + threadIdx.x) * 2;
    int n0 = t0 & (NPOS - 1);
    const float sc = 1.f / 32768.f;
    float xs0  = (n0 >= 1) ? (float)x_int[t0 - 1] * sc : 0.f;
    float xs1  = (float)x_int[t0] * sc;
    float xsp0 = (n0 >= 2) ? (float)x_int[t0 - 2] * sc : 0.f;
    float xsp1 = xs0;
#pragma unroll
    for (int c = 0; c < 16; ++c) {
        float2 o;
        o.x = xs0 + W0[c * 2 + 0] * xsp0 + W0[c * 2 + 1] * xs0 + b0[c];
        o.y = xs1 + W0[c * 2 + 0] * xsp1 + W0[c * 2 + 1] * xs1 + b0[c];
        *(float2*)(h + (size_t)c * TOTAL + t0) = o;
    }
}

// ================= one residual layer (float2 vectorized) =================
__global__ __launch_bounds__(256, 2) void layer_kernel2(
    const float* __restrict__ hIn, float* __restrict__ hOut,
    float* __restrict__ skip,
    const float* __restrict__ wf, const float* __restrict__ bfv,
    const float* __restrict__ wg, const float* __restrict__ bgv,
    const float* __restrict__ wsk, const float* __restrict__ bskv,
    int d, int firstLayer)
{
    int t0 = (blockIdx.x * 256 + threadIdx.x) * 2;
    int n0 = t0 & (NPOS - 1);

    float2 hc[16], hp[16];
#pragma unroll
    for (int ic = 0; ic < 16; ++ic)
        hc[ic] = *(const float2*)(hIn + (size_t)ic * TOTAL + t0);

    if (d == 1) {
        bool v = (n0 >= 1);
        int tm = v ? (t0 - 1) : t0;
#pragma unroll
        for (int ic = 0; ic < 16; ++ic) {
            float x = hIn[(size_t)ic * TOTAL + tm];
            hp[ic].x = v ? x : 0.f;
            hp[ic].y = hc[ic].x;
        }
    } else {
        bool v = (n0 >= d);
        int tm = v ? (t0 - d) : t0;
#pragma unroll
        for (int ic = 0; ic < 16; ++ic) {
            float2 x = *(const float2*)(hIn + (size_t)ic * TOTAL + tm);
            hp[ic].x = v ? x.x : 0.f;
            hp[ic].y = v ? x.y : 0.f;
        }
    }

    float2 fa[16], ga[16];
#pragma unroll
    for (int c = 0; c < 16; ++c) {
        fa[c].x = fa[c].y = bfv[c];
        ga[c].x = ga[c].y = bgv[c];
    }
#pragma unroll
    for (int c = 0; c < 16; ++c) {
#pragma unroll
        for (int ic = 0; ic < 16; ++ic) {
            float wf0 = wf[(c * 16 + ic) * 2 + 0];
            float wf1 = wf[(c * 16 + ic) * 2 + 1];
            float wg0 = wg[(c * 16 + ic) * 2 + 0];
            float wg1 = wg[(c * 16 + ic) * 2 + 1];
            fa[c].x = fmaf(wf0, hp[ic].x, fa[c].x);
            fa[c].x = fmaf(wf1, hc[ic].x, fa[c].x);
            fa[c].y = fmaf(wf0, hp[ic].y, fa[c].y);
            fa[c].y = fmaf(wf1, hc[ic].y, fa[c].y);
            ga[c].x = fmaf(wg0, hp[ic].x, ga[c].x);
            ga[c].x = fmaf(wg1, hc[ic].x, ga[c].x);
            ga[c].y = fmaf(wg0, hp[ic].y, ga[c].y);
            ga[c].y = fmaf(wg1, hc[ic].y, ga[c].y);
        }
    }

#pragma unroll
    for (int c = 0; c < 16; ++c) {
        float2 o;
        o.x = fmaf(fast_tanh(fa[c].x), fast_sigmoid(ga[c].x), hc[c].x);
        o.y = fmaf(fast_tanh(fa[c].y), fast_sigmoid(ga[c].y), hc[c].y);
        *(float2*)(hOut + (size_t)c * TOTAL + t0) = o;
    }

    // skip accumulation from PRE-update h (hc)
#pragma unroll
    for (int sch = 0; sch < 32; ++sch) {
        float2 acc;
        acc.x = acc.y = bskv[sch];
#pragma unroll
        for (int ic = 0; ic < 16; ++ic) {
            float w = wsk[sch * 16 + ic];
            acc.x = fmaf(w, hc[ic].x, acc.x);
            acc.y = fmaf(w, hc[ic].y, acc.y);
        }
        float* sp = skip + (size_t)sch * TOTAL + t0;
        if (firstLayer) {
            *(float2*)sp = acc;
        } else {
            float2 old = *(const float2*)sp;
            acc.x += old.x; acc.y += old.y;
            *(float2*)sp = acc;
        }
    }
}

// ================= final: relu(skip)->agg64->relu->logits256->log_softmax ====
// block = 256 thr = 4 waves over 64 positions (lane = position).
// stage1: wave w computes agg channels [16w,16w+16) -> LDS (conflict-free).
// stage2: wave w holds ALL 64 of its class accumulators in regs (acc[64],
//         statically indexed); agg read ONCE per value via av[16] chunks in a
//         non-unrolled ict loop (64 ds_reads/thread total). No bf16 stash —
//         logits stay in regs until the single coalesced write.
__global__ __launch_bounds__(256, 3) void final_kernel(
    const float* __restrict__ skip,
    const float* __restrict__ Wagg, const float* __restrict__ bagg,
    const float* __restrict__ Wout, const float* __restrict__ bout,
    float* __restrict__ out)
{
    __shared__ float agg_lds[64][64];
    __shared__ float red_m[64][5];   // padded: stride 5 -> conflict-free
    __shared__ float red_s[64][5];

    int lane = threadIdx.x & 63;
    int cgw  = threadIdx.x >> 6;
    int pos  = blockIdx.x * 64 + lane;
    int n = pos & (NPOS - 1);
    int b = pos >> LOG2N;

    // ---- stage 1: cooperative agg
    float sv[32];
#pragma unroll
    for (int sch = 0; sch < 32; ++sch)
        sv[sch] = fmaxf(skip[(size_t)sch * TOTAL + pos], 0.f);

#pragma unroll
    for (int a = 0; a < 16; ++a) {
        int ac = cgw * 16 + a;
        float acc = bagg[ac];
#pragma unroll
        for (int sch = 0; sch < 32; ++sch)
            acc = fmaf(Wagg[ac * 32 + sch], sv[sch], acc);
        agg_lds[ac][lane] = fmaxf(acc, 0.f);
    }
    __syncthreads();

    // ---- stage 2: 64 classes per wave, acc[64] in registers
    int c0 = cgw * 64;
    float acc[64];
#pragma unroll
    for (int j = 0; j < 64; ++j) acc[j] = bout[c0 + j];

#pragma unroll 1
    for (int ict = 0; ict < 4; ++ict) {
        float av[16];
#pragma unroll
        for (int ii = 0; ii < 16; ++ii) av[ii] = agg_lds[ict * 16 + ii][lane];
        const float* wbase = Wout + (size_t)c0 * 64 + ict * 16;
#pragma unroll
        for (int j = 0; j < 64; ++j) {
#pragma unroll
            for (int ii = 0; ii < 16; ++ii)
                acc[j] = fmaf(wbase[j * 64 + ii], av[ii], acc[j]);
        }
    }

    // ---- per-wave softmax stats over acc[64]
    float m = acc[0];
#pragma unroll
    for (int j = 1; j < 64; ++j) m = fmaxf(m, acc[j]);
    float s = 0.f;
#pragma unroll
    for (int j = 0; j < 64; ++j) s += __expf(acc[j] - m);

    // ---- cross-wave combine
    red_m[lane][cgw] = m;
    red_s[lane][cgw] = s;
    __syncthreads();
    float M = fmaxf(fmaxf(red_m[lane][0], red_m[lane][1]),
                    fmaxf(red_m[lane][2], red_m[lane][3]));
    float S = 0.f;
#pragma unroll
    for (int k = 0; k < 4; ++k) S += red_s[lane][k] * __expf(red_m[lane][k] - M);
    float logZ = M + __logf(S);

    // ---- single write of shifted logits
    float* ob = out + ((size_t)(b * 256 + c0)) * NPOS + n;
#pragma unroll
    for (int j = 0; j < 64; ++j)
        ob[(size_t)j * NPOS] = acc[j] - logZ;
}

extern "C" void kernel_launch(void* const* d_in, const int* in_sizes, int n_in,
                              void* d_out, int out_size, void* d_ws, size_t ws_size,
                              hipStream_t stream)
{
    const int*   x_int = (const int*)  d_in[0];
    const float* W0    = (const float*)d_in[1];
    const float* b0    = (const float*)d_in[2];
    const float* Wf    = (const float*)d_in[3];
    const float* bfv   = (const float*)d_in[4];
    const float* Wg    = (const float*)d_in[5];
    const float* bgv   = (const float*)d_in[6];
    const float* Wsk   = (const float*)d_in[7];
    const float* bskv  = (const float*)d_in[8];
    const float* Wagg  = (const float*)d_in[9];
    const float* bagg  = (const float*)d_in[10];
    const float* Wout  = (const float*)d_in[11];
    const float* bout  = (const float*)d_in[12];
    float* out = (float*)d_out;

    const size_t hE  = (size_t)16 * TOTAL;  // 16 MiB
    const size_t skE = (size_t)32 * TOTAL;  // 32 MiB

    // skip must NOT live in d_out (final_kernel reads skip while writing out).
    // h ping-pong MAY live in the out tail (dead before final_kernel runs).
    float* skipb = (float*)d_ws;
    float *hA, *hB;
    if (ws_size >= (skE + 2 * hE) * sizeof(float)) {
        hA = skipb + skE;
        hB = hA + hE;
    } else {
        hA = out + ((size_t)out_size - 2 * hE);
        hB = hA + hE;
    }

    const int grid2 = TOTAL / (256 * 2);   // 512 blocks, 2 positions/thread

    init_kernel2<<<grid2, 256, 0, stream>>>(x_int, W0, b0, hA);

    float* hin = hA;
    float* hout = hB;
    for (int i = 0; i < 19; ++i) {
        int d = 1 << ((i + 1) % 10);
        layer_kernel2<<<grid2, 256, 0, stream>>>(
            hin, hout, skipb,
            Wf + (size_t)i * 512, bfv + (size_t)i * 16,
            Wg + (size_t)i * 512, bgv + (size_t)i * 16,
            Wsk + (size_t)i * 512, bskv + (size_t)i * 32,
            d, (i == 0) ? 1 : 0);
        float* tmp = hin; hin = hout; hout = tmp;
    }

    final_kernel<<<TOTAL / 64, 256, 0, stream>>>(skipb, Wagg, bagg, Wout, bout, out);
}

// Round 8
// 823.057 us; speedup vs baseline: 2.1434x; 1.5088x over previous
//
#include <hip/hip_runtime.h>
#include <math.h>
#include <stdint.h>

#define NPOS  32768
#define LOG2N 15
#define BATCH 8
#define TOTAL (BATCH * NPOS)   // 262144 positions

typedef __attribute__((ext_vector_type(8))) short short8v;  // 8 bf16 = 4 VGPR
typedef __attribute__((ext_vector_type(4))) float f32x4;    // MFMA C/D

__device__ __forceinline__ float fast_tanh(float x) {
    float t = __expf(-2.f * x);
    return fmaf(2.f, __builtin_amdgcn_rcpf(1.f + t), -1.f);
}
__device__ __forceinline__ float fast_sigmoid(float x) {
    return __builtin_amdgcn_rcpf(1.f + __expf(-x));
}
__device__ __forceinline__ unsigned short bf16rne(float x) {
    unsigned u = __float_as_uint(x);
    u = (u + 0x7fffu + ((u >> 16) & 1u)) >> 16;
    return (unsigned short)u;
}

// ================= init =================
__global__ __launch_bounds__(256) void init_kernel2(
    const int* __restrict__ x_int, const float* __restrict__ W0,
    const float* __restrict__ b0, float* __restrict__ h)
{
    int t0 = (blockIdx.x * 256 + threadIdx.x) * 2;
    int n0 = t0 & (NPOS - 1);
    const float sc = 1.f / 32768.f;
    float xs0  = (n0 >= 1) ? (float)x_int[t0 - 1] * sc : 0.f;
    float xs1  = (float)x_int[t0] * sc;
    float xsp0 = (n0 >= 2) ? (float)x_int[t0 - 2] * sc : 0.f;
    float xsp1 = xs0;
#pragma unroll
    for (int c = 0; c < 16; ++c) {
        float2 o;
        o.x = xs0 + W0[c * 2 + 0] * xsp0 + W0[c * 2 + 1] * xs0 + b0[c];
        o.y = xs1 + W0[c * 2 + 0] * xsp1 + W0[c * 2 + 1] * xs1 + b0[c];
        *(float2*)(h + (size_t)c * TOTAL + t0) = o;
    }
}

// ================= one residual layer (float2 vectorized) =================
__global__ __launch_bounds__(256, 2) void layer_kernel2(
    const float* __restrict__ hIn, float* __restrict__ hOut,
    float* __restrict__ skip,
    const float* __restrict__ wf, const float* __restrict__ bfv,
    const float* __restrict__ wg, const float* __restrict__ bgv,
    const float* __restrict__ wsk, const float* __restrict__ bskv,
    int d, int firstLayer)
{
    int t0 = (blockIdx.x * 256 + threadIdx.x) * 2;
    int n0 = t0 & (NPOS - 1);

    float2 hc[16], hp[16];
#pragma unroll
    for (int ic = 0; ic < 16; ++ic)
        hc[ic] = *(const float2*)(hIn + (size_t)ic * TOTAL + t0);

    if (d == 1) {
        bool v = (n0 >= 1);
        int tm = v ? (t0 - 1) : t0;
#pragma unroll
        for (int ic = 0; ic < 16; ++ic) {
            float x = hIn[(size_t)ic * TOTAL + tm];
            hp[ic].x = v ? x : 0.f;
            hp[ic].y = hc[ic].x;
        }
    } else {
        bool v = (n0 >= d);
        int tm = v ? (t0 - d) : t0;
#pragma unroll
        for (int ic = 0; ic < 16; ++ic) {
            float2 x = *(const float2*)(hIn + (size_t)ic * TOTAL + tm);
            hp[ic].x = v ? x.x : 0.f;
            hp[ic].y = v ? x.y : 0.f;
        }
    }

    float2 fa[16], ga[16];
#pragma unroll
    for (int c = 0; c < 16; ++c) {
        fa[c].x = fa[c].y = bfv[c];
        ga[c].x = ga[c].y = bgv[c];
    }
#pragma unroll
    for (int c = 0; c < 16; ++c) {
#pragma unroll
        for (int ic = 0; ic < 16; ++ic) {
            float wf0 = wf[(c * 16 + ic) * 2 + 0];
            float wf1 = wf[(c * 16 + ic) * 2 + 1];
            float wg0 = wg[(c * 16 + ic) * 2 + 0];
            float wg1 = wg[(c * 16 + ic) * 2 + 1];
            fa[c].x = fmaf(wf0, hp[ic].x, fa[c].x);
            fa[c].x = fmaf(wf1, hc[ic].x, fa[c].x);
            fa[c].y = fmaf(wf0, hp[ic].y, fa[c].y);
            fa[c].y = fmaf(wf1, hc[ic].y, fa[c].y);
            ga[c].x = fmaf(wg0, hp[ic].x, ga[c].x);
            ga[c].x = fmaf(wg1, hc[ic].x, ga[c].x);
            ga[c].y = fmaf(wg0, hp[ic].y, ga[c].y);
            ga[c].y = fmaf(wg1, hc[ic].y, ga[c].y);
        }
    }

#pragma unroll
    for (int c = 0; c < 16; ++c) {
        float2 o;
        o.x = fmaf(fast_tanh(fa[c].x), fast_sigmoid(ga[c].x), hc[c].x);
        o.y = fmaf(fast_tanh(fa[c].y), fast_sigmoid(ga[c].y), hc[c].y);
        *(float2*)(hOut + (size_t)c * TOTAL + t0) = o;
    }

    // skip accumulation from PRE-update h (hc)
#pragma unroll
    for (int sch = 0; sch < 32; ++sch) {
        float2 acc;
        acc.x = acc.y = bskv[sch];
#pragma unroll
        for (int ic = 0; ic < 16; ++ic) {
            float w = wsk[sch * 16 + ic];
            acc.x = fmaf(w, hc[ic].x, acc.x);
            acc.y = fmaf(w, hc[ic].y, acc.y);
        }
        float* sp = skip + (size_t)sch * TOTAL + t0;
        if (firstLayer) {
            *(float2*)sp = acc;
        } else {
            float2 old = *(const float2*)sp;
            acc.x += old.x; acc.y += old.y;
            *(float2*)sp = acc;
        }
    }
}

// ================= final: relu(skip)->agg64->relu->logits256->log_softmax ====
// block = 256 thr = 4 waves over 64 positions.
// Stage 1 (VALU): wave w computes agg ch [16w,16w+16) per position (lane=pos),
//   relu, bf16-pack, swizzled LDS store as B^T layout [pos][ic].
// Stage 2 (MFMA 16x16x32 bf16): wave w owns classes [64w,64w+64).
//   A-frags = Wout rows (bf16, converted in-kernel, 8 frags in VGPRs),
//   B-frags = agg from LDS (conflict-free swizzled ds_read_b128),
//   C preloaded with bias. D: col=lane&15 (pos), row=(lane>>4)*4+reg (class).
__global__ __launch_bounds__(256, 2) void final_kernel(
    const float* __restrict__ skip,
    const float* __restrict__ Wagg, const float* __restrict__ bagg,
    const float* __restrict__ Wout, const float* __restrict__ bout,
    float* __restrict__ out)
{
    __shared__ unsigned short agg_bu[64 * 64];  // [pos][ic] bf16, 16B-slot swizzled
    __shared__ float red_m[64][5];
    __shared__ float red_s[64][5];

    int tid  = threadIdx.x;
    int lane = tid & 63;
    int w    = tid >> 6;          // wave id (uniform)
    int posG = blockIdx.x * 64;
    int b    = posG >> LOG2N;
    int nb   = posG & (NPOS - 1);

    // ---- stage 1: agg (VALU), thread = (pos=lane, channel group w)
    {
        int pos = posG + lane;
        float sv[32];
#pragma unroll
        for (int sch = 0; sch < 32; ++sch)
            sv[sch] = fmaxf(skip[(size_t)sch * TOTAL + pos], 0.f);

        float r16[16];
#pragma unroll
        for (int a = 0; a < 16; ++a) {
            int ac = w * 16 + a;
            float acc = bagg[ac];
#pragma unroll
            for (int sch = 0; sch < 32; ++sch)
                acc = fmaf(Wagg[ac * 32 + sch], sv[sch], acc);
            r16[a] = fmaxf(acc, 0.f);
        }
        // pack pairs -> swizzled LDS ([pos][ic] bf16, slot^((pos&7)<<4))
#pragma unroll
        for (int q = 0; q < 8; ++q) {
            unsigned pk = (unsigned)bf16rne(r16[2 * q]) |
                          ((unsigned)bf16rne(r16[2 * q + 1]) << 16);
            int icbyte = (w * 16 + 2 * q) * 2;             // 32w + 4q
            int addr   = lane * 128 + (icbyte ^ ((lane & 7) << 4));
            *(unsigned*)(&agg_bu[addr >> 1]) = pk;
        }
    }
    __syncthreads();

    // ---- stage 2: MFMA logits
    int lr = lane & 15;   // D col / A row / B col
    int lg = lane >> 4;   // k-group (frags) and D row-group

    // A-frags: Wout[class][k], class = c0+ct*16+lr, k = kf*32+lg*8 (+0..7)
    int c0 = w * 64;
    short8v afr[4][2];
#pragma unroll
    for (int ct = 0; ct < 4; ++ct) {
#pragma unroll
        for (int kf = 0; kf < 2; ++kf) {
            int cls = c0 + ct * 16 + lr;
            int k0  = kf * 32 + lg * 8;
            const float4* wp = (const float4*)(Wout + (size_t)cls * 64 + k0);
            float4 w0 = wp[0], w1 = wp[1];
            short8v af;
            af[0] = (short)bf16rne(w0.x); af[1] = (short)bf16rne(w0.y);
            af[2] = (short)bf16rne(w0.z); af[3] = (short)bf16rne(w0.w);
            af[4] = (short)bf16rne(w1.x); af[5] = (short)bf16rne(w1.y);
            af[6] = (short)bf16rne(w1.z); af[7] = (short)bf16rne(w1.w);
            afr[ct][kf] = af;
        }
    }

    f32x4 acc[4][4];  // [pt][ct]
#pragma unroll
    for (int pt = 0; pt < 4; ++pt) {
        // B-frags: agg[pos][k], pos = pt*16+lr, k = kf*32+lg*8 (+0..7)
        int pos = pt * 16 + lr;
        int sw  = (pos & 7) << 4;
        const short8v* bp0 = (const short8v*)(&agg_bu[(pos * 128 + ((0 * 64 + lg * 16) ^ sw)) >> 1]);
        const short8v* bp1 = (const short8v*)(&agg_bu[(pos * 128 + ((1 * 64 + lg * 16) ^ sw)) >> 1]);
        short8v bf0 = *bp0;
        short8v bf1 = *bp1;
#pragma unroll
        for (int ct = 0; ct < 4; ++ct) {
            f32x4 c;
#pragma unroll
            for (int r = 0; r < 4; ++r) c[r] = bout[c0 + ct * 16 + lg * 4 + r];
            c = __builtin_amdgcn_mfma_f32_16x16x32_bf16(afr[ct][0], bf0, c, 0, 0, 0);
            c = __builtin_amdgcn_mfma_f32_16x16x32_bf16(afr[ct][1], bf1, c, 0, 0, 0);
            acc[pt][ct] = c;
        }
    }

    // ---- softmax stats: per lane 16 class-values per position (4 ct x 4 reg)
#pragma unroll
    for (int pt = 0; pt < 4; ++pt) {
        float m = -1e30f;
#pragma unroll
        for (int ct = 0; ct < 4; ++ct)
#pragma unroll
            for (int r = 0; r < 4; ++r) m = fmaxf(m, acc[pt][ct][r]);
        m = fmaxf(m, __shfl_xor(m, 16));
        m = fmaxf(m, __shfl_xor(m, 32));
        float s = 0.f;
#pragma unroll
        for (int ct = 0; ct < 4; ++ct)
#pragma unroll
            for (int r = 0; r < 4; ++r) s += __expf(acc[pt][ct][r] - m);
        s += __shfl_xor(s, 16);
        s += __shfl_xor(s, 32);
        int pos = pt * 16 + lr;
        red_m[pos][w] = m;
        red_s[pos][w] = s;
    }
    __syncthreads();

    // ---- cross-wave combine + write
#pragma unroll
    for (int pt = 0; pt < 4; ++pt) {
        int pos = pt * 16 + lr;
        float M = fmaxf(fmaxf(red_m[pos][0], red_m[pos][1]),
                        fmaxf(red_m[pos][2], red_m[pos][3]));
        float S = 0.f;
#pragma unroll
        for (int k = 0; k < 4; ++k) S += red_s[pos][k] * __expf(red_m[pos][k] - M);
        float logZ = M + __logf(S);

        int n = nb + pos;
#pragma unroll
        for (int ct = 0; ct < 4; ++ct) {
#pragma unroll
            for (int r = 0; r < 4; ++r) {
                int cls = c0 + ct * 16 + lg * 4 + r;
                out[((size_t)(b * 256 + cls)) * NPOS + n] = acc[pt][ct][r] - logZ;
            }
        }
    }
}

extern "C" void kernel_launch(void* const* d_in, const int* in_sizes, int n_in,
                              void* d_out, int out_size, void* d_ws, size_t ws_size,
                              hipStream_t stream)
{
    const int*   x_int = (const int*)  d_in[0];
    const float* W0    = (const float*)d_in[1];
    const float* b0    = (const float*)d_in[2];
    const float* Wf    = (const float*)d_in[3];
    const float* bfv   = (const float*)d_in[4];
    const float* Wg    = (const float*)d_in[5];
    const float* bgv   = (const float*)d_in[6];
    const float* Wsk   = (const float*)d_in[7];
    const float* bskv  = (const float*)d_in[8];
    const float* Wagg  = (const float*)d_in[9];
    const float* bagg  = (const float*)d_in[10];
    const float* Wout  = (const float*)d_in[11];
    const float* bout  = (const float*)d_in[12];
    float* out = (float*)d_out;

    const size_t hE  = (size_t)16 * TOTAL;  // 16 MiB
    const size_t skE = (size_t)32 * TOTAL;  // 32 MiB

    float* skipb = (float*)d_ws;
    float *hA, *hB;
    if (ws_size >= (skE + 2 * hE) * sizeof(float)) {
        hA = skipb + skE;
        hB = hA + hE;
    } else {
        hA = out + ((size_t)out_size - 2 * hE);
        hB = hA + hE;
    }

    const int grid2 = TOTAL / (256 * 2);   // 512 blocks, 2 positions/thread

    init_kernel2<<<grid2, 256, 0, stream>>>(x_int, W0, b0, hA);

    float* hin = hA;
    float* hout = hB;
    for (int i = 0; i < 19; ++i) {
        int d = 1 << ((i + 1) % 10);
        layer_kernel2<<<grid2, 256, 0, stream>>>(
            hin, hout, skipb,
            Wf + (size_t)i * 512, bfv + (size_t)i * 16,
            Wg + (size_t)i * 512, bgv + (size_t)i * 16,
            Wsk + (size_t)i * 512, bskv + (size_t)i * 32,
            d, (i == 0) ? 1 : 0);
        float* tmp = hin; hin = hout; hout = tmp;
    }

    final_kernel<<<TOTAL / 64, 256, 0, stream>>>(skipb, Wagg, bagg, Wout, bout, out);
}